// Round 4
// baseline (1777.480 us; speedup 1.0000x reference)
//
#include <hip/hip_runtime.h>
#include <hip/hip_bf16.h>
#include <math.h>

#define T_ 1024
#define D_ 256
#define N_ 8192
#define NH_ 4
#define NLAYER_ 6
#define VOCAB_ 256
#define TWO_PI_F 6.283185307179586f

typedef __attribute__((ext_vector_type(8))) short short8;
typedef __attribute__((ext_vector_type(4))) float floatx4;
typedef unsigned short ushort_t;

// ---------- async global->LDS 16B ----------
__device__ __forceinline__ void cp16(const void* g, void* l) {
    __builtin_amdgcn_global_load_lds((const __attribute__((address_space(1))) unsigned int*)g,
                                     (__attribute__((address_space(3))) unsigned int*)l,
                                     16, 0, 0);
}

__device__ __forceinline__ float bf2f_raw(unsigned short u) {
    union { unsigned int i; float f; } x;
    x.i = ((unsigned int)u) << 16;
    return x.f;
}
__device__ __forceinline__ unsigned short f2bf_u(float f) {
    union { float f; unsigned int u; } x; x.f = f;
    unsigned int r = (x.u + 0x7fffu + ((x.u >> 16) & 1u)) >> 16;
    return (unsigned short)r;
}
// both lanes of a column pair build the same packed bf16x2 word
__device__ __forceinline__ unsigned int pack_pair_bf(float mine, int odd) {
    float other = __shfl_xor(mine, 1);
    unsigned short a = f2bf_u(odd ? other : mine);
    unsigned short b = f2bf_u(odd ? mine : other);
    return (unsigned int)a | ((unsigned int)b << 16);
}
__device__ __forceinline__ float2 pack_pair_f2(float mine, int odd) {
    float other = __shfl_xor(mine, 1);
    return odd ? make_float2(other, mine) : make_float2(mine, other);
}

// ---------- block reduce ----------
__device__ __forceinline__ float block_sum(float v, float* red) {
    int tid = threadIdx.x;
    red[tid] = v;
    __syncthreads();
    #pragma unroll
    for (int s = 128; s > 0; s >>= 1) {
        if (tid < s) red[tid] += red[tid + s];
        __syncthreads();
    }
    float r = red[0];
    __syncthreads();
    return r;
}

// ---------- LN kernels ----------

__global__ void k_embed_ln(const int* __restrict__ idx, const float* __restrict__ ew,
                           float* __restrict__ x, __hip_bfloat16* __restrict__ x_bf) {
    __shared__ float red[256];
    int t = blockIdx.x, d = threadIdx.x;
    float v = ew[idx[t] * D_ + d];
    float mean = block_sum(v, red) * (1.0f / D_);
    float c = v - mean;
    float var = block_sum(c * c, red) * (1.0f / D_);
    float o = c * rsqrtf(var + 1e-5f);
    x[t * D_ + d] = o;
    x_bf[t * D_ + d] = __float2bfloat16(o);
}

// LN over sum of 2 ykv split-K partials -> bf16
__global__ void k_ln_rows(const float* __restrict__ yp, __hip_bfloat16* __restrict__ outb) {
    __shared__ float red[256];
    int r = blockIdx.x, d = threadIdx.x;
    const size_t S = (size_t)NH_ * T_ * D_;
    float v = yp[(size_t)r * D_ + d] + yp[S + (size_t)r * D_ + d];
    float mean = block_sum(v, red) * (1.0f / D_);
    float c = v - mean;
    float var = block_sum(c * c, red) * (1.0f / D_);
    outb[(size_t)r * D_ + d] = __float2bfloat16(c * rsqrtf(var + 1e-5f));
}

// x = ln(x + ln(sum of 32 ymlp partials)); emit fp32 + bf16
__global__ void k_x_update(float* __restrict__ x, const float* __restrict__ ypart,
                           __hip_bfloat16* __restrict__ x_bf) {
    __shared__ float red[256];
    int t = blockIdx.x, d = threadIdx.x;
    float v = 0.0f;
    #pragma unroll
    for (int i = 0; i < 32; i++) v += ypart[(size_t)i * T_ * D_ + t * D_ + d];
    float m1 = block_sum(v, red) * (1.0f / D_);
    float c1 = v - m1;
    float v1 = block_sum(c1 * c1, red) * (1.0f / D_);
    float u = c1 * rsqrtf(v1 + 1e-5f);
    float w = x[t * D_ + d] + u;
    float m2 = block_sum(w, red) * (1.0f / D_);
    float c2 = w - m2;
    float v2 = block_sum(c2 * c2, red) * (1.0f / D_);
    float o = c2 * rsqrtf(v2 + 1e-5f);
    x[t * D_ + d] = o;
    x_bf[t * D_ + d] = __float2bfloat16(o);
}

// ---------- transpose+convert: fp32 [h][R][C] -> bf16 [h][C][R] ----------
__global__ __launch_bounds__(256) void k_tcvt(const float* __restrict__ in,
                                              __hip_bfloat16* __restrict__ out,
                                              int R, int C) {
    int h = blockIdx.z;
    int r0 = blockIdx.y * 32, c0 = blockIdx.x * 32;
    __shared__ float tile[32][33];
    int tx = threadIdx.x & 31, ty = threadIdx.x >> 5;
    const float* inh = in + (size_t)h * R * C;
    __hip_bfloat16* outh = out + (size_t)h * R * C;
    #pragma unroll
    for (int i = 0; i < 4; i++)
        tile[ty + 8 * i][tx] = inh[(size_t)(r0 + ty + 8 * i) * C + c0 + tx];
    __syncthreads();
    #pragma unroll
    for (int i = 0; i < 4; i++)
        outh[(size_t)(c0 + ty + 8 * i) * R + r0 + tx] = __float2bfloat16(tile[tx][ty + 8 * i]);
}

// ---------- one-time RoPE table: packed (cos,sin) bf16 per (t, pair j) ----------
__global__ void k_rope_tab(unsigned int* __restrict__ tab) {
    int idx = blockIdx.x * 256 + threadIdx.x;  // T_ * 4096 entries
    int t = idx >> 12, j = idx & 4095;         // freq = 2^(-j/256) / 2pi
    float freq = exp2f((float)j * (-1.0f / 256.0f)) * 0.15915494309189535f;
    float ph = (float)t * freq;
    ph -= floorf(ph);
    float s, c;
    __sincosf(ph * TWO_PI_F, &s, &c);
    tab[idx] = (unsigned int)f2bf_u(c) | ((unsigned int)f2bf_u(s) << 16);
}

// ---------- core: 128x128 A·B^T bf16 MFMA tile, BK=64, XOR-swizzled LDS ----------
__device__ __forceinline__ void gemm128(const ushort_t* __restrict__ A,
                                        const ushort_t* __restrict__ B,
                                        int lda, int ldb, int K,
                                        ushort_t* As, ushort_t* Bs,
                                        floatx4 acc[4][4]) {
    const int tid = threadIdx.x;
    const int lane = tid & 63, wid = tid >> 6;
    const int wm = wid >> 1, wn = wid & 1;
    const int quad = lane >> 4, col = lane & 15;
    int srow[4], scol[4];
    #pragma unroll
    for (int i = 0; i < 4; i++) {
        int s = i * 256 + tid;
        srow[i] = s >> 3;
        scol[i] = (s & 7) ^ (srow[i] & 7);  // XOR swizzle (involutive)
    }
    for (int k0 = 0; k0 < K; k0 += 64) {
        #pragma unroll
        for (int i = 0; i < 4; i++)
            cp16(A + (size_t)srow[i] * lda + k0 + scol[i] * 8,
                 As + (size_t)(i * 256 + wid * 64) * 8);
        #pragma unroll
        for (int i = 0; i < 4; i++)
            cp16(B + (size_t)srow[i] * ldb + k0 + scol[i] * 8,
                 Bs + (size_t)(i * 256 + wid * 64) * 8);
        __syncthreads();
        #pragma unroll
        for (int kk = 0; kk < 2; kk++) {
            short8 af[4], bf[4];
            #pragma unroll
            for (int mi = 0; mi < 4; mi++) {
                int row = wm * 64 + mi * 16 + col;
                int pc = ((kk << 2) + quad) ^ (row & 7);
                af[mi] = *(const short8*)&As[row * 64 + pc * 8];
            }
            #pragma unroll
            for (int ni = 0; ni < 4; ni++) {
                int row = wn * 64 + ni * 16 + col;
                int pc = ((kk << 2) + quad) ^ (row & 7);
                bf[ni] = *(const short8*)&Bs[row * 64 + pc * 8];
            }
            #pragma unroll
            for (int mi = 0; mi < 4; mi++)
                #pragma unroll
                for (int ni = 0; ni < 4; ni++)
                    acc[mi][ni] = __builtin_amdgcn_mfma_f32_16x16x32_bf16(
                        af[mi], bf[ni], acc[mi][ni], 0, 0, 0);
        }
        __syncthreads();
    }
}

#define GEMM_PROLOGUE()                                              \
    __shared__ __align__(16) ushort_t As[128 * 64];                  \
    __shared__ __align__(16) ushort_t Bs[128 * 64];                  \
    floatx4 acc[4][4];                                               \
    _Pragma("unroll") for (int mi = 0; mi < 4; mi++)                 \
        _Pragma("unroll") for (int ni = 0; ni < 4; ni++)             \
            acc[mi][ni] = (floatx4){0.f, 0.f, 0.f, 0.f};             \
    const int lane = threadIdx.x & 63, wid = threadIdx.x >> 6;       \
    const int wm = wid >> 1, wn = wid & 1;                           \
    const int quad = lane >> 4, col = lane & 15;                     \
    const int odd = lane & 1;

// ---------- scores: qr @ qr^T, triangular 128-tiles, split-K=4, bf16 partials ----------
__global__ __launch_bounds__(256) void k_scores_m(const __hip_bfloat16* __restrict__ qr,
                                                  __hip_bfloat16* __restrict__ scp) {
    int i = blockIdx.x;
    int ti = 0;
    while ((ti + 1) * (ti + 2) / 2 <= i) ti++;
    int si = i - ti * (ti + 1) / 2;
    const int t0 = ti * 128, s0 = si * 128;
    const int h = blockIdx.y, ks = blockIdx.z;  // ks slowest for L2 grouping
    GEMM_PROLOGUE();
    const ushort_t* qh = (const ushort_t*)qr + (size_t)h * T_ * N_ + (size_t)ks * (N_ / 4);
    gemm128(qh + (size_t)t0 * N_, qh + (size_t)s0 * N_, N_, N_, N_ / 4, As, Bs, acc);
    unsigned int* sch = (unsigned int*)(scp + (size_t)ks * NH_ * T_ * T_ + (size_t)h * T_ * T_);
    const int rsel = odd ? 2 : 0;
    #pragma unroll
    for (int mi = 0; mi < 4; mi++)
        #pragma unroll
        for (int ni = 0; ni < 4; ni++) {
            const int ss = s0 + wn * 64 + ni * 16 + col;
            const int ss_e = ss & ~1;
            unsigned int w[4];
            #pragma unroll
            for (int r = 0; r < 4; r++) {
                int tt = t0 + wm * 64 + mi * 16 + quad * 4 + r;
                float v = (ss < tt) ? acc[mi][ni][r] : 0.0f;
                w[r] = pack_pair_bf(v, odd);
            }
            #pragma unroll
            for (int rr = 0; rr < 2; rr++) {
                int r = rsel + rr;
                int tt = t0 + wm * 64 + mi * 16 + quad * 4 + r;
                sch[((size_t)tt * T_ + ss_e) >> 1] = w[r];
            }
        }
}

// sum the 4 split-K partials into split 0 (u32/bf16x2 packed)
__global__ void k_sc_cvt(__hip_bfloat16* __restrict__ scp) {
    int i = blockIdx.x;
    int ti = 0;
    while ((ti + 1) * (ti + 2) / 2 <= i) ti++;
    int si = i - ti * (ti + 1) / 2;
    const size_t S2h = (size_t)NH_ * T_ * T_ / 2;  // u32 stride between splits
    unsigned int* sp = (unsigned int*)scp;
    size_t b = (size_t)blockIdx.y * T_ * T_ / 2;
    for (int e = threadIdx.x; e < 128 * 64; e += 256) {
        int r = e >> 6, c = e & 63;
        size_t off = b + (((size_t)(ti * 128 + r) * T_ + si * 128) >> 1) + c;
        float lo = 0.f, hi = 0.f;
        #pragma unroll
        for (int s = 0; s < 4; s++) {
            unsigned int w = sp[off + s * S2h];
            lo += bf2f_raw((unsigned short)(w & 0xffff));
            hi += bf2f_raw((unsigned short)(w >> 16));
        }
        sp[off] = (unsigned int)f2bf_u(lo) | ((unsigned int)f2bf_u(hi) << 16);
    }
}

// ---------- proj: A_bf[rows,256] @ Wt[h][n][256]^T, 128-tiles, packed stores ----------
template <int MODE>
__global__ __launch_bounds__(256) void k_proj_m(const __hip_bfloat16* __restrict__ Abf,
                                                const __hip_bfloat16* __restrict__ Wt,
                                                __hip_bfloat16* __restrict__ out1,
                                                __hip_bfloat16* __restrict__ out2,
                                                const __hip_bfloat16* __restrict__ xsp,
                                                const unsigned int* __restrict__ rtab) {
    const int h = blockIdx.z;
    const int t0 = blockIdx.y * 128, n0 = blockIdx.x * 128;
    GEMM_PROLOGUE();
    const ushort_t* Ah = (const ushort_t*)Abf + (MODE ? (size_t)h * T_ * D_ : (size_t)0)
                         + (size_t)t0 * D_;
    const ushort_t* Bh = (const ushort_t*)Wt + (size_t)h * N_ * D_ + (size_t)n0 * D_;
    gemm128(Ah, Bh, D_, D_, D_, As, Bs, acc);
    const int rsel = odd ? 2 : 0;
    unsigned int* o1 = (unsigned int*)out1;
    unsigned int* o2 = (unsigned int*)out2;
    #pragma unroll
    for (int mi = 0; mi < 4; mi++)
        #pragma unroll
        for (int ni = 0; ni < 4; ni++) {
            const int nn = n0 + wn * 64 + ni * 16 + col;
            const int nn_e = nn & ~1;
            unsigned int w1[4], w2[4];
            #pragma unroll
            for (int r = 0; r < 4; r++) {
                int tt = t0 + wm * 64 + mi * 16 + quad * 4 + r;
                size_t off = ((size_t)h * T_ + tt) * (size_t)N_ + nn;
                float v = fmaxf(acc[mi][ni][r], 0.0f);
                if (MODE == 0) {
                    float vp = __shfl_xor(v, 1);
                    float ve = odd ? vp : v, vo = odd ? v : vp;
                    w1[r] = (unsigned int)f2bf_u(ve) | ((unsigned int)f2bf_u(vo) << 16);
                    unsigned int cs = rtab[(size_t)tt * 4096 + (nn >> 1)];
                    float c = bf2f_raw((unsigned short)(cs & 0xffff));
                    float s = bf2f_raw((unsigned short)(cs >> 16));
                    float oe = ve * c - vo * s;
                    float oo = vo * c + ve * s;
                    w2[r] = (unsigned int)f2bf_u(oe) | ((unsigned int)f2bf_u(oo) << 16);
                } else {
                    float xs = __bfloat162float(xsp[off]);
                    w1[r] = pack_pair_bf(v * xs, odd);
                }
            }
            #pragma unroll
            for (int rr = 0; rr < 2; rr++) {
                int r = rsel + rr;
                int tt = t0 + wm * 64 + mi * 16 + quad * 4 + r;
                size_t o32 = (((size_t)h * T_ + tt) * (size_t)N_ + nn_e) >> 1;
                o1[o32] = w1[r];
                if (MODE == 0) o2[o32] = w2[r];
            }
        }
}

// ---------- ykv: sc_bf[h] @ xT^T (MFMA), K causal-bounded, split-K=2 ----------
__global__ __launch_bounds__(256) void k_ykv_m(const __hip_bfloat16* __restrict__ sc,
                                               const __hip_bfloat16* __restrict__ xT,
                                               float* __restrict__ ykvp) {
    const int d0 = blockIdx.x * 128, t0 = blockIdx.y * 128;
    const int h = blockIdx.z >> 1, ks = blockIdx.z & 1;
    GEMM_PROLOGUE();
    const int half = (t0 + 128) >> 1;  // multiple of 64
    const ushort_t* Ah = (const ushort_t*)sc + (size_t)h * T_ * T_ + (size_t)t0 * T_ + ks * half;
    const ushort_t* Bh = (const ushort_t*)xT + (size_t)d0 * T_ + ks * half;
    gemm128(Ah, Bh, T_, T_, half, As, Bs, acc);
    float2* yp = (float2*)(ykvp + (size_t)ks * NH_ * T_ * D_);
    const int rsel = odd ? 2 : 0;
    #pragma unroll
    for (int mi = 0; mi < 4; mi++)
        #pragma unroll
        for (int ni = 0; ni < 4; ni++) {
            const int dd_e = (d0 + wn * 64 + ni * 16 + col) & ~1;
            float2 w[4];
            #pragma unroll
            for (int r = 0; r < 4; r++) w[r] = pack_pair_f2(acc[mi][ni][r], odd);
            #pragma unroll
            for (int rr = 0; rr < 2; rr++) {
                int r = rsel + rr;
                int tt = t0 + wm * 64 + mi * 16 + quad * 4 + r;
                yp[(((size_t)h * T_ + tt) * D_ + dd_e) >> 1] = w[r];
            }
        }
}

// ---------- ymlp: xy[h] @ decT[h]^T, split-K=8 into 32 partial buffers ----------
__global__ __launch_bounds__(256) void k_ymlp_m(const __hip_bfloat16* __restrict__ xy,
                                                const __hip_bfloat16* __restrict__ decT,
                                                float* __restrict__ ypart) {
    const int d0 = blockIdx.x * 128, t0 = blockIdx.y * 128;
    const int ks = blockIdx.z >> 2, h = blockIdx.z & 3;  // ks slowest
    GEMM_PROLOGUE();
    const ushort_t* Ah = (const ushort_t*)xy + (size_t)h * T_ * N_ + (size_t)t0 * N_ + ks * 1024;
    const ushort_t* Bh = (const ushort_t*)decT + (size_t)h * D_ * N_ + (size_t)d0 * N_ + ks * 1024;
    gemm128(Ah, Bh, N_, N_, 1024, As, Bs, acc);
    float2* yp = (float2*)(ypart + (size_t)blockIdx.z * T_ * D_);
    const int rsel = odd ? 2 : 0;
    #pragma unroll
    for (int mi = 0; mi < 4; mi++)
        #pragma unroll
        for (int ni = 0; ni < 4; ni++) {
            const int dd_e = (d0 + wn * 64 + ni * 16 + col) & ~1;
            float2 w[4];
            #pragma unroll
            for (int r = 0; r < 4; r++) w[r] = pack_pair_f2(acc[mi][ni][r], odd);
            #pragma unroll
            for (int rr = 0; rr < 2; rr++) {
                int r = rsel + rr;
                int tt = t0 + wm * 64 + mi * 16 + quad * 4 + r;
                yp[((size_t)tt * D_ + dd_e) >> 1] = w[r];
            }
        }
}

// ---------- lm_head: x_bf @ lmT^T (MFMA), fp32 out ----------
__global__ __launch_bounds__(256) void k_lmhead_m(const __hip_bfloat16* __restrict__ x_bf,
                                                  const __hip_bfloat16* __restrict__ lmT,
                                                  float* __restrict__ out) {
    const int v0 = blockIdx.x * 128, t0 = blockIdx.y * 128;
    GEMM_PROLOGUE();
    const ushort_t* Ah = (const ushort_t*)x_bf + (size_t)t0 * D_;
    const ushort_t* Bh = (const ushort_t*)lmT + (size_t)v0 * D_;
    gemm128(Ah, Bh, D_, D_, D_, As, Bs, acc);
    float2* op = (float2*)out;
    const int rsel = odd ? 2 : 0;
    #pragma unroll
    for (int mi = 0; mi < 4; mi++)
        #pragma unroll
        for (int ni = 0; ni < 4; ni++) {
            const int vv_e = (v0 + wn * 64 + ni * 16 + col) & ~1;
            float2 w[4];
            #pragma unroll
            for (int r = 0; r < 4; r++) w[r] = pack_pair_f2(acc[mi][ni][r], odd);
            #pragma unroll
            for (int rr = 0; rr < 2; rr++) {
                int r = rsel + rr;
                int tt = t0 + wm * 64 + mi * 16 + quad * 4 + r;
                op[((size_t)tt * VOCAB_ + vv_e) >> 1] = w[r];
            }
        }
}

// ---------- launch ----------

extern "C" void kernel_launch(void* const* d_in, const int* in_sizes, int n_in,
                              void* d_out, int out_size, void* d_ws, size_t ws_size,
                              hipStream_t stream) {
    const int* idx = (const int*)d_in[0];
    const float* embed_w = (const float*)d_in[1];
    const float* encoder = (const float*)d_in[2];
    const float* encoder_v = (const float*)d_in[3];
    const float* decoder = (const float*)d_in[4];
    const float* lm_head = (const float*)d_in[5];
    float* out = (float*)d_out;

    char* p = (char*)d_ws;
    auto alloc = [&](size_t bytes) {
        char* q = p;
        p += (bytes + 255) & ~(size_t)255;
        return q;
    };
    float* x = (float*)alloc((size_t)T_ * D_ * 4);
    __hip_bfloat16* x_bf = (__hip_bfloat16*)alloc((size_t)T_ * D_ * 2);
    __hip_bfloat16* xT = (__hip_bfloat16*)alloc((size_t)T_ * D_ * 2);
    __hip_bfloat16* ykv_bf = (__hip_bfloat16*)alloc((size_t)NH_ * T_ * D_ * 2);
    __hip_bfloat16* scp = (__hip_bfloat16*)alloc((size_t)4 * NH_ * T_ * T_ * 2);
    __hip_bfloat16* xsp = (__hip_bfloat16*)alloc((size_t)NH_ * T_ * N_ * 2);
    __hip_bfloat16* qr = (__hip_bfloat16*)alloc((size_t)NH_ * T_ * N_ * 2);  // reused as xy
    __hip_bfloat16* encT = (__hip_bfloat16*)alloc((size_t)NH_ * N_ * D_ * 2);
    __hip_bfloat16* encvT = (__hip_bfloat16*)alloc((size_t)NH_ * N_ * D_ * 2);
    __hip_bfloat16* decT = (__hip_bfloat16*)alloc((size_t)NH_ * N_ * D_ * 2);
    __hip_bfloat16* lmT = (__hip_bfloat16*)alloc((size_t)VOCAB_ * D_ * 2);
    unsigned int* rtab = (unsigned int*)alloc((size_t)T_ * 4096 * 4);
    // aliases (disjoint lifetimes):
    float* ypart = (float*)xsp;               // 32 MB; xsp dead after k_proj_m<1>
    float* ykvp = (float*)(scp + (size_t)NH_ * T_ * T_);  // 8 MB in scp splits 1-2;
                                              // live only k_ykv_m -> k_ln_rows (after k_sc_cvt)

    // one-time: weight transposes + rope table
    k_tcvt<<<dim3(N_ / 32, D_ / 32, NH_), 256, 0, stream>>>(encoder, encT, D_, N_);
    k_tcvt<<<dim3(N_ / 32, D_ / 32, NH_), 256, 0, stream>>>(encoder_v, encvT, D_, N_);
    k_tcvt<<<dim3(D_ / 32, N_ / 32, NH_), 256, 0, stream>>>(decoder, decT, N_, D_);
    k_tcvt<<<dim3(VOCAB_ / 32, D_ / 32, 1), 256, 0, stream>>>(lm_head, lmT, D_, VOCAB_);
    k_rope_tab<<<T_ * 4096 / 256, 256, 0, stream>>>(rtab);

    k_embed_ln<<<T_, 256, 0, stream>>>(idx, embed_w, x, x_bf);
    for (int l = 0; l < NLAYER_; l++) {
        k_proj_m<0><<<dim3(N_ / 128, T_ / 128, NH_), 256, 0, stream>>>(x_bf, encT, xsp, qr,
                                                                       nullptr, rtab);
        k_scores_m<<<dim3(36, NH_, 4), 256, 0, stream>>>(qr, scp);
        k_sc_cvt<<<dim3(36, NH_), 256, 0, stream>>>(scp);
        k_tcvt<<<dim3(D_ / 32, T_ / 32, 1), 256, 0, stream>>>(x, xT, T_, D_);
        k_ykv_m<<<dim3(D_ / 128, T_ / 128, NH_ * 2), 256, 0, stream>>>(scp, xT, ykvp);
        k_ln_rows<<<NH_ * T_, 256, 0, stream>>>(ykvp, ykv_bf);
        k_proj_m<1><<<dim3(N_ / 128, T_ / 128, NH_), 256, 0, stream>>>(ykv_bf, encvT, qr /*xy*/,
                                                                       nullptr, xsp, rtab);
        k_ymlp_m<<<dim3(D_ / 128, T_ / 128, NH_ * 8), 256, 0, stream>>>(qr, decT, ypart);
        k_x_update<<<T_, 256, 0, stream>>>(x, ypart, x_bf);
    }
    k_lmhead_m<<<dim3(VOCAB_ / 128, T_ / 128), 256, 0, stream>>>(x_bf, lmT, out);
}

// Round 5
// 1325.623 us; speedup vs baseline: 1.3409x; 1.3409x over previous
//
#include <hip/hip_runtime.h>
#include <hip/hip_bf16.h>
#include <math.h>

#define T_ 1024
#define D_ 256
#define N_ 8192
#define NH_ 4
#define NLAYER_ 6
#define VOCAB_ 256
#define TWO_PI_F 6.283185307179586f

typedef __attribute__((ext_vector_type(8))) short short8;
typedef __attribute__((ext_vector_type(4))) float floatx4;
typedef unsigned short ushort_t;

// ---------- async global->LDS 16B ----------
__device__ __forceinline__ void cp16(const void* g, void* l) {
    __builtin_amdgcn_global_load_lds((const __attribute__((address_space(1))) unsigned int*)g,
                                     (__attribute__((address_space(3))) unsigned int*)l,
                                     16, 0, 0);
}

__device__ __forceinline__ float bf2f_raw(unsigned short u) {
    union { unsigned int i; float f; } x;
    x.i = ((unsigned int)u) << 16;
    return x.f;
}
__device__ __forceinline__ unsigned int f2bf_u(float f) {
    union { float f; unsigned int u; } x; x.f = f;
    return (x.u + 0x7fffu + ((x.u >> 16) & 1u)) >> 16;
}

// ---------- block reduce ----------
__device__ __forceinline__ float block_sum(float v, float* red) {
    int tid = threadIdx.x;
    red[tid] = v;
    __syncthreads();
    #pragma unroll
    for (int s = 128; s > 0; s >>= 1) {
        if (tid < s) red[tid] += red[tid + s];
        __syncthreads();
    }
    float r = red[0];
    __syncthreads();
    return r;
}

// ---------- LN kernels ----------

__global__ void k_embed_ln(const int* __restrict__ idx, const float* __restrict__ ew,
                           float* __restrict__ x, __hip_bfloat16* __restrict__ x_bf) {
    __shared__ float red[256];
    int t = blockIdx.x, d = threadIdx.x;
    float v = ew[idx[t] * D_ + d];
    float mean = block_sum(v, red) * (1.0f / D_);
    float c = v - mean;
    float var = block_sum(c * c, red) * (1.0f / D_);
    float o = c * rsqrtf(var + 1e-5f);
    x[t * D_ + d] = o;
    x_bf[t * D_ + d] = __float2bfloat16(o);
}

// LN over sum of 2 ykv split-K partials -> bf16
__global__ void k_ln_rows(const float* __restrict__ yp, __hip_bfloat16* __restrict__ outb) {
    __shared__ float red[256];
    int r = blockIdx.x, d = threadIdx.x;
    const size_t S = (size_t)NH_ * T_ * D_;
    float v = yp[(size_t)r * D_ + d] + yp[S + (size_t)r * D_ + d];
    float mean = block_sum(v, red) * (1.0f / D_);
    float c = v - mean;
    float var = block_sum(c * c, red) * (1.0f / D_);
    outb[(size_t)r * D_ + d] = __float2bfloat16(c * rsqrtf(var + 1e-5f));
}

// x = ln(x + ln(sum of 32 ymlp partials)); emit fp32 + bf16
__global__ void k_x_update(float* __restrict__ x, const float* __restrict__ ypart,
                           __hip_bfloat16* __restrict__ x_bf) {
    __shared__ float red[256];
    int t = blockIdx.x, d = threadIdx.x;
    float v = 0.0f;
    #pragma unroll
    for (int i = 0; i < 32; i++) v += ypart[(size_t)i * T_ * D_ + t * D_ + d];
    float m1 = block_sum(v, red) * (1.0f / D_);
    float c1 = v - m1;
    float v1 = block_sum(c1 * c1, red) * (1.0f / D_);
    float u = c1 * rsqrtf(v1 + 1e-5f);
    float w = x[t * D_ + d] + u;
    float m2 = block_sum(w, red) * (1.0f / D_);
    float c2 = w - m2;
    float v2 = block_sum(c2 * c2, red) * (1.0f / D_);
    float o = c2 * rsqrtf(v2 + 1e-5f);
    x[t * D_ + d] = o;
    x_bf[t * D_ + d] = __float2bfloat16(o);
}

// ---------- transpose+convert: fp32 [h][R][C] -> bf16 [h][C][R] ----------
__global__ __launch_bounds__(256) void k_tcvt(const float* __restrict__ in,
                                              __hip_bfloat16* __restrict__ out,
                                              int R, int C) {
    int h = blockIdx.z;
    int r0 = blockIdx.y * 32, c0 = blockIdx.x * 32;
    __shared__ float tile[32][33];
    int tx = threadIdx.x & 31, ty = threadIdx.x >> 5;
    const float* inh = in + (size_t)h * R * C;
    __hip_bfloat16* outh = out + (size_t)h * R * C;
    #pragma unroll
    for (int i = 0; i < 4; i++)
        tile[ty + 8 * i][tx] = inh[(size_t)(r0 + ty + 8 * i) * C + c0 + tx];
    __syncthreads();
    #pragma unroll
    for (int i = 0; i < 4; i++)
        outh[(size_t)(c0 + ty + 8 * i) * R + r0 + tx] = __float2bfloat16(tile[tx][ty + 8 * i]);
}

// ---------- one-time RoPE table: packed (cos,sin) bf16 per (t, pair j) ----------
__global__ void k_rope_tab(unsigned int* __restrict__ tab) {
    int idx = blockIdx.x * 256 + threadIdx.x;  // T_ * 4096 entries
    int t = idx >> 12, j = idx & 4095;         // freq = 2^(-j/256) / 2pi
    float freq = exp2f((float)j * (-1.0f / 256.0f)) * 0.15915494309189535f;
    float ph = (float)t * freq;
    ph -= floorf(ph);
    float s, c;
    __sincosf(ph * TWO_PI_F, &s, &c);
    tab[idx] = f2bf_u(c) | (f2bf_u(s) << 16);
}

// ---------- core: 128x128 A·B^T bf16 MFMA tile, BK=64, XOR-swizzled LDS ----------
__device__ __forceinline__ void gemm128(const ushort_t* __restrict__ A,
                                        const ushort_t* __restrict__ B,
                                        int lda, int ldb, int K,
                                        ushort_t* As, ushort_t* Bs,
                                        floatx4 acc[4][4]) {
    const int tid = threadIdx.x;
    const int lane = tid & 63, wid = tid >> 6;
    const int wm = wid >> 1, wn = wid & 1;
    const int quad = lane >> 4, col = lane & 15;
    int srow[4], scol[4];
    #pragma unroll
    for (int i = 0; i < 4; i++) {
        int s = i * 256 + tid;
        srow[i] = s >> 3;
        scol[i] = (s & 7) ^ (srow[i] & 7);  // XOR swizzle (involutive)
    }
    for (int k0 = 0; k0 < K; k0 += 64) {
        #pragma unroll
        for (int i = 0; i < 4; i++)
            cp16(A + (size_t)srow[i] * lda + k0 + scol[i] * 8,
                 As + (size_t)(i * 256 + wid * 64) * 8);
        #pragma unroll
        for (int i = 0; i < 4; i++)
            cp16(B + (size_t)srow[i] * ldb + k0 + scol[i] * 8,
                 Bs + (size_t)(i * 256 + wid * 64) * 8);
        __syncthreads();
        #pragma unroll
        for (int kk = 0; kk < 2; kk++) {
            short8 af[4], bf[4];
            #pragma unroll
            for (int mi = 0; mi < 4; mi++) {
                int row = wm * 64 + mi * 16 + col;
                int pc = ((kk << 2) + quad) ^ (row & 7);
                af[mi] = *(const short8*)&As[row * 64 + pc * 8];
            }
            #pragma unroll
            for (int ni = 0; ni < 4; ni++) {
                int row = wn * 64 + ni * 16 + col;
                int pc = ((kk << 2) + quad) ^ (row & 7);
                bf[ni] = *(const short8*)&Bs[row * 64 + pc * 8];
            }
            #pragma unroll
            for (int mi = 0; mi < 4; mi++)
                #pragma unroll
                for (int ni = 0; ni < 4; ni++)
                    acc[mi][ni] = __builtin_amdgcn_mfma_f32_16x16x32_bf16(
                        af[mi], bf[ni], acc[mi][ni], 0, 0, 0);
        }
        __syncthreads();
    }
}

#define GEMM_PROLOGUE()                                              \
    __shared__ __align__(16) ushort_t As[128 * 64];                  \
    __shared__ __align__(16) ushort_t Bs[128 * 64];                  \
    floatx4 acc[4][4];                                               \
    _Pragma("unroll") for (int mi = 0; mi < 4; mi++)                 \
        _Pragma("unroll") for (int ni = 0; ni < 4; ni++)             \
            acc[mi][ni] = (floatx4){0.f, 0.f, 0.f, 0.f};             \
    const int lane = threadIdx.x & 63, wid = threadIdx.x >> 6;       \
    const int wm = wid >> 1, wn = wid & 1;                           \
    const int quad = lane >> 4, col = lane & 15;                     \
    const int odd = lane & 1;                                        \
    const int rsel = odd ? 2 : 0, rother = odd ? 0 : 2;

// ---------- scores: qr @ qr^T, triangular 128-tiles, split-K=4, bf16 partials ----------
// 1D grid 576: slice (h,ks) = b & 15 -> fixed (b mod 8) -> one XCD per slice (L2 locality)
__global__ __launch_bounds__(256) void k_scores_m(const __hip_bfloat16* __restrict__ qr,
                                                  __hip_bfloat16* __restrict__ scp) {
    const int b = blockIdx.x;
    const int ks = b & 3, h = (b >> 2) & 3;
    int i = b >> 4;
    int ti = 0;
    while ((ti + 1) * (ti + 2) / 2 <= i) ti++;
    int si = i - ti * (ti + 1) / 2;
    const int t0 = ti * 128, s0 = si * 128;
    GEMM_PROLOGUE();
    const ushort_t* qh = (const ushort_t*)qr + (size_t)h * T_ * N_ + (size_t)ks * (N_ / 4);
    gemm128(qh + (size_t)t0 * N_, qh + (size_t)s0 * N_, N_, N_, N_ / 4, As, Bs, acc);
    unsigned int* sch = (unsigned int*)(scp + (size_t)ks * NH_ * T_ * T_ + (size_t)h * T_ * T_);
    #pragma unroll
    for (int mi = 0; mi < 4; mi++)
        #pragma unroll
        for (int ni = 0; ni < 4; ni++) {
            const int ss = s0 + wn * 64 + ni * 16 + col;
            const int ss_e = ss & ~1;
            const int rowb = t0 + wm * 64 + mi * 16 + quad * 4;
            #pragma unroll
            for (int rr = 0; rr < 2; rr++) {
                int tt_o = rowb + rother + rr;
                float send = (ss < tt_o) ? acc[mi][ni][rother + rr] : 0.0f;
                float recv = __shfl_xor(send, 1);
                int tt = rowb + rsel + rr;
                float mine = (ss < tt) ? acc[mi][ni][rsel + rr] : 0.0f;
                float lo = odd ? recv : mine, hi = odd ? mine : recv;
                sch[((size_t)tt * T_ + ss_e) >> 1] = f2bf_u(lo) | (f2bf_u(hi) << 16);
            }
        }
}

// sum the 4 split-K partials into split 0 (u32/bf16x2 packed)
__global__ void k_sc_cvt(__hip_bfloat16* __restrict__ scp) {
    int i = blockIdx.x;
    int ti = 0;
    while ((ti + 1) * (ti + 2) / 2 <= i) ti++;
    int si = i - ti * (ti + 1) / 2;
    const size_t S2h = (size_t)NH_ * T_ * T_ / 2;  // u32 stride between splits
    unsigned int* sp = (unsigned int*)scp;
    size_t b = (size_t)blockIdx.y * T_ * T_ / 2;
    for (int e = threadIdx.x; e < 128 * 64; e += 256) {
        int r = e >> 6, c = e & 63;
        size_t off = b + (((size_t)(ti * 128 + r) * T_ + si * 128) >> 1) + c;
        float lo = 0.f, hi = 0.f;
        #pragma unroll
        for (int s = 0; s < 4; s++) {
            unsigned int w = sp[off + s * S2h];
            lo += bf2f_raw((unsigned short)(w & 0xffff));
            hi += bf2f_raw((unsigned short)(w >> 16));
        }
        sp[off] = f2bf_u(lo) | (f2bf_u(hi) << 16);
    }
}

// ---------- proj: A_bf[rows,256] @ Wt[h][n][256]^T, 128-tiles, packed stores ----------
template <int MODE>
__global__ __launch_bounds__(256) void k_proj_m(const __hip_bfloat16* __restrict__ Abf,
                                                const __hip_bfloat16* __restrict__ Wt,
                                                __hip_bfloat16* __restrict__ out1,
                                                __hip_bfloat16* __restrict__ out2,
                                                const __hip_bfloat16* __restrict__ xsp,
                                                const unsigned int* __restrict__ rtab) {
    const int h = blockIdx.z;
    const int t0 = blockIdx.y * 128, n0 = blockIdx.x * 128;
    GEMM_PROLOGUE();
    const ushort_t* Ah = (const ushort_t*)Abf + (MODE ? (size_t)h * T_ * D_ : (size_t)0)
                         + (size_t)t0 * D_;
    const ushort_t* Bh = (const ushort_t*)Wt + (size_t)h * N_ * D_ + (size_t)n0 * D_;
    gemm128(Ah, Bh, D_, D_, D_, As, Bs, acc);
    unsigned int* o1 = (unsigned int*)out1;
    unsigned int* o2 = (unsigned int*)out2;
    #pragma unroll
    for (int mi = 0; mi < 4; mi++)
        #pragma unroll
        for (int ni = 0; ni < 4; ni++) {
            const int nn_e = (n0 + wn * 64 + ni * 16 + col) & ~1;
            const int rowb = t0 + wm * 64 + mi * 16 + quad * 4;
            #pragma unroll
            for (int rr = 0; rr < 2; rr++) {
                float send = fmaxf(acc[mi][ni][rother + rr], 0.0f);
                float recv = __shfl_xor(send, 1);
                float mine = fmaxf(acc[mi][ni][rsel + rr], 0.0f);
                float ve = odd ? recv : mine, vo = odd ? mine : recv;
                int tt = rowb + rsel + rr;
                size_t o32 = (((size_t)h * T_ + tt) * (size_t)N_ + nn_e) >> 1;
                if (MODE == 0) {
                    o1[o32] = f2bf_u(ve) | (f2bf_u(vo) << 16);
                    unsigned int cs = rtab[(size_t)tt * 4096 + (nn_e >> 1)];
                    float c = bf2f_raw((unsigned short)(cs & 0xffff));
                    float s = bf2f_raw((unsigned short)(cs >> 16));
                    o2[o32] = f2bf_u(ve * c - vo * s) | (f2bf_u(vo * c + ve * s) << 16);
                } else {
                    unsigned int xw = ((const unsigned int*)xsp)[o32];
                    float xe = bf2f_raw((unsigned short)(xw & 0xffff));
                    float xo = bf2f_raw((unsigned short)(xw >> 16));
                    o1[o32] = f2bf_u(ve * xe) | (f2bf_u(vo * xo) << 16);
                }
            }
        }
}

// ---------- ykv: sc_bf[h] @ xT^T (MFMA), K causal-bounded, split-K=2 ----------
// 1D grid 128: slice (h,ks) = b & 7 -> XCD-confined
__global__ __launch_bounds__(256) void k_ykv_m(const __hip_bfloat16* __restrict__ sc,
                                               const __hip_bfloat16* __restrict__ xT,
                                               float* __restrict__ ykvp) {
    const int b = blockIdx.x;
    const int h = (b >> 1) & 3, ks = b & 1;
    const int r0 = b >> 3;
    const int d0 = (r0 & 1) * 128, t0 = (r0 >> 1) * 128;
    GEMM_PROLOGUE();
    const int half = (t0 + 128) >> 1;  // multiple of 64
    const ushort_t* Ah = (const ushort_t*)sc + (size_t)h * T_ * T_ + (size_t)t0 * T_ + ks * half;
    const ushort_t* Bh = (const ushort_t*)xT + (size_t)d0 * T_ + ks * half;
    gemm128(Ah, Bh, T_, T_, half, As, Bs, acc);
    float2* yp = (float2*)(ykvp + (size_t)ks * NH_ * T_ * D_);
    #pragma unroll
    for (int mi = 0; mi < 4; mi++)
        #pragma unroll
        for (int ni = 0; ni < 4; ni++) {
            const int dd_e = (d0 + wn * 64 + ni * 16 + col) & ~1;
            const int rowb = t0 + wm * 64 + mi * 16 + quad * 4;
            #pragma unroll
            for (int rr = 0; rr < 2; rr++) {
                float send = acc[mi][ni][rother + rr];
                float recv = __shfl_xor(send, 1);
                float mine = acc[mi][ni][rsel + rr];
                int tt = rowb + rsel + rr;
                yp[(((size_t)h * T_ + tt) * D_ + dd_e) >> 1] =
                    odd ? make_float2(recv, mine) : make_float2(mine, recv);
            }
        }
}

// ---------- ymlp: xy[h] @ decT[h]^T, split-K=8 into 32 partial buffers ----------
// 1D grid 512: slice (ks,h) = b & 31 -> XCD-confined (dec slice reused across 8 t0)
__global__ __launch_bounds__(256) void k_ymlp_m(const __hip_bfloat16* __restrict__ xy,
                                                const __hip_bfloat16* __restrict__ decT,
                                                float* __restrict__ ypart) {
    const int b = blockIdx.x;
    const int slice = b & 31;
    const int ks = slice >> 2, h = slice & 3;
    const int r0 = b >> 5;
    const int d0 = (r0 & 1) * 128, t0 = (r0 >> 1) * 128;
    GEMM_PROLOGUE();
    const ushort_t* Ah = (const ushort_t*)xy + (size_t)h * T_ * N_ + (size_t)t0 * N_ + ks * 1024;
    const ushort_t* Bh = (const ushort_t*)decT + (size_t)h * D_ * N_ + (size_t)d0 * N_ + ks * 1024;
    gemm128(Ah, Bh, N_, N_, 1024, As, Bs, acc);
    float2* yp = (float2*)(ypart + (size_t)slice * T_ * D_);
    #pragma unroll
    for (int mi = 0; mi < 4; mi++)
        #pragma unroll
        for (int ni = 0; ni < 4; ni++) {
            const int dd_e = (d0 + wn * 64 + ni * 16 + col) & ~1;
            const int rowb = t0 + wm * 64 + mi * 16 + quad * 4;
            #pragma unroll
            for (int rr = 0; rr < 2; rr++) {
                float send = acc[mi][ni][rother + rr];
                float recv = __shfl_xor(send, 1);
                float mine = acc[mi][ni][rsel + rr];
                int tt = rowb + rsel + rr;
                yp[((size_t)tt * D_ + dd_e) >> 1] =
                    odd ? make_float2(recv, mine) : make_float2(mine, recv);
            }
        }
}

// ---------- lm_head: x_bf @ lmT^T (MFMA), fp32 out ----------
__global__ __launch_bounds__(256) void k_lmhead_m(const __hip_bfloat16* __restrict__ x_bf,
                                                  const __hip_bfloat16* __restrict__ lmT,
                                                  float* __restrict__ out) {
    const int v0 = blockIdx.x * 128, t0 = blockIdx.y * 128;
    GEMM_PROLOGUE();
    const ushort_t* Ah = (const ushort_t*)x_bf + (size_t)t0 * D_;
    const ushort_t* Bh = (const ushort_t*)lmT + (size_t)v0 * D_;
    gemm128(Ah, Bh, D_, D_, D_, As, Bs, acc);
    float2* op = (float2*)out;
    #pragma unroll
    for (int mi = 0; mi < 4; mi++)
        #pragma unroll
        for (int ni = 0; ni < 4; ni++) {
            const int vv_e = (v0 + wn * 64 + ni * 16 + col) & ~1;
            const int rowb = t0 + wm * 64 + mi * 16 + quad * 4;
            #pragma unroll
            for (int rr = 0; rr < 2; rr++) {
                float send = acc[mi][ni][rother + rr];
                float recv = __shfl_xor(send, 1);
                float mine = acc[mi][ni][rsel + rr];
                int tt = rowb + rsel + rr;
                op[((size_t)tt * VOCAB_ + vv_e) >> 1] =
                    odd ? make_float2(recv, mine) : make_float2(mine, recv);
            }
        }
}

// ---------- launch ----------

extern "C" void kernel_launch(void* const* d_in, const int* in_sizes, int n_in,
                              void* d_out, int out_size, void* d_ws, size_t ws_size,
                              hipStream_t stream) {
    const int* idx = (const int*)d_in[0];
    const float* embed_w = (const float*)d_in[1];
    const float* encoder = (const float*)d_in[2];
    const float* encoder_v = (const float*)d_in[3];
    const float* decoder = (const float*)d_in[4];
    const float* lm_head = (const float*)d_in[5];
    float* out = (float*)d_out;

    char* p = (char*)d_ws;
    auto alloc = [&](size_t bytes) {
        char* q = p;
        p += (bytes + 255) & ~(size_t)255;
        return q;
    };
    float* x = (float*)alloc((size_t)T_ * D_ * 4);
    __hip_bfloat16* x_bf = (__hip_bfloat16*)alloc((size_t)T_ * D_ * 2);
    __hip_bfloat16* xT = (__hip_bfloat16*)alloc((size_t)T_ * D_ * 2);
    __hip_bfloat16* ykv_bf = (__hip_bfloat16*)alloc((size_t)NH_ * T_ * D_ * 2);
    __hip_bfloat16* scp = (__hip_bfloat16*)alloc((size_t)4 * NH_ * T_ * T_ * 2);
    __hip_bfloat16* xsp = (__hip_bfloat16*)alloc((size_t)NH_ * T_ * N_ * 2);
    __hip_bfloat16* qr = (__hip_bfloat16*)alloc((size_t)NH_ * T_ * N_ * 2);  // reused as xy
    __hip_bfloat16* encT = (__hip_bfloat16*)alloc((size_t)NH_ * N_ * D_ * 2);
    __hip_bfloat16* encvT = (__hip_bfloat16*)alloc((size_t)NH_ * N_ * D_ * 2);
    __hip_bfloat16* decT = (__hip_bfloat16*)alloc((size_t)NH_ * N_ * D_ * 2);
    __hip_bfloat16* lmT = (__hip_bfloat16*)alloc((size_t)VOCAB_ * D_ * 2);
    unsigned int* rtab = (unsigned int*)alloc((size_t)T_ * 4096 * 4);
    // aliases (disjoint lifetimes):
    float* ypart = (float*)xsp;               // 32 MB; xsp dead after k_proj_m<1>
    float* ykvp = (float*)(scp + (size_t)NH_ * T_ * T_);  // 16 MB in scp splits 1-2;
                                              // live only k_ykv_m -> k_ln_rows (after k_sc_cvt)

    // one-time: weight transposes + rope table
    k_tcvt<<<dim3(N_ / 32, D_ / 32, NH_), 256, 0, stream>>>(encoder, encT, D_, N_);
    k_tcvt<<<dim3(N_ / 32, D_ / 32, NH_), 256, 0, stream>>>(encoder_v, encvT, D_, N_);
    k_tcvt<<<dim3(D_ / 32, N_ / 32, NH_), 256, 0, stream>>>(decoder, decT, N_, D_);
    k_tcvt<<<dim3(VOCAB_ / 32, D_ / 32, 1), 256, 0, stream>>>(lm_head, lmT, D_, VOCAB_);
    k_rope_tab<<<T_ * 4096 / 256, 256, 0, stream>>>(rtab);

    k_embed_ln<<<T_, 256, 0, stream>>>(idx, embed_w, x, x_bf);
    for (int l = 0; l < NLAYER_; l++) {
        k_proj_m<0><<<dim3(N_ / 128, T_ / 128, NH_), 256, 0, stream>>>(x_bf, encT, xsp, qr,
                                                                       nullptr, rtab);
        k_scores_m<<<36 * 16, 256, 0, stream>>>(qr, scp);
        k_sc_cvt<<<dim3(36, NH_), 256, 0, stream>>>(scp);
        k_tcvt<<<dim3(D_ / 32, T_ / 32, 1), 256, 0, stream>>>(x, xT, T_, D_);
        k_ykv_m<<<16 * 8, 256, 0, stream>>>(scp, xT, ykvp);
        k_ln_rows<<<NH_ * T_, 256, 0, stream>>>(ykvp, ykv_bf);
        k_proj_m<1><<<dim3(N_ / 128, T_ / 128, NH_), 256, 0, stream>>>(ykv_bf, encvT, qr /*xy*/,
                                                                       nullptr, xsp, rtab);
        k_ymlp_m<<<16 * 32, 256, 0, stream>>>(qr, decT, ypart);
        k_x_update<<<T_, 256, 0, stream>>>(x, ypart, x_bf);
    }
    k_lmhead_m<<<dim3(VOCAB_ / 128, T_ / 128), 256, 0, stream>>>(x_bf, lmT, out);
}